// Round 7
// baseline (894.435 us; speedup 1.0000x reference)
//
#include <hip/hip_runtime.h>

typedef unsigned int uint;
typedef unsigned short ushort;
typedef __attribute__((ext_vector_type(8))) short short8;
typedef __attribute__((ext_vector_type(4))) float f32x4;
typedef __attribute__((ext_vector_type(2))) float f32x2;

#define D 128

__device__ __forceinline__ float bf2f(ushort h){ return __uint_as_float(((uint)h)<<16); }
__device__ __forceinline__ ushort f2bf(float f){
  uint u = __float_as_uint(f);
  u += 0x7fff + ((u >> 16) & 1);   // RNE
  return (ushort)(u >> 16);
}
__device__ __forceinline__ float ldf(const void* p, long i, int bf){
  return bf ? bf2f(((const ushort*)p)[i]) : ((const float*)p)[i];
}
__device__ __forceinline__ int imin(int a, int b){ return a < b ? a : b; }

// ---------------- dtype detection ----------------
__global__ __launch_bounds__(256) void detect_kernel(const uint* __restrict__ xw,
                                                     int* __restrict__ flag){
  __shared__ int cnt;
  if (threadIdx.x == 0) cnt = 0;
  __syncthreads();
  uint w = xw[threadIdx.x];
  int ef = (int)((w >> 7) & 0xffu);
  if (ef >= 90 && ef <= 142) atomicAdd(&cnt, 1);
  __syncthreads();
  if (threadIdx.x == 0) flag[0] = (cnt >= 128) ? 1 : 0;
}

// ---------------- CSR build (dst/src are layer-invariant) ----------------
__global__ __launch_bounds__(256) void hist_kernel(const int* __restrict__ dst,
                                                   int* __restrict__ deg, int E_){
  int e = blockIdx.x*256 + threadIdx.x;
  if (e < E_) atomicAdd(&deg[dst[e]], 1);
}

__global__ __launch_bounds__(256) void scan1_kernel(const int* __restrict__ deg,
                                                    int* __restrict__ rs,
                                                    int* __restrict__ bsum, int Nn){
  __shared__ int s[256];
  int tid = threadIdx.x;
  int base = blockIdx.x*512;
  int i0 = base + 2*tid, i1 = i0 + 1;
  int a = (i0 < Nn) ? deg[i0] : 0;
  int b = (i1 < Nn) ? deg[i1] : 0;
  int p = a + b;
  s[tid] = p; __syncthreads();
  for (int off = 1; off < 256; off <<= 1){
    int t = (tid >= off) ? s[tid-off] : 0;
    __syncthreads();
    s[tid] += t;
    __syncthreads();
  }
  int ex = s[tid] - p;
  if (i0 < Nn) rs[i0] = ex;
  if (i1 < Nn) rs[i1] = ex + a;
  if (tid == 255) bsum[blockIdx.x] = s[255];
}

__global__ __launch_bounds__(256) void scan2_kernel(const int* __restrict__ bsum,
                                                    int* __restrict__ boff, int NB){
  __shared__ int s[256];
  int tid = threadIdx.x;
  int v = (tid < NB) ? bsum[tid] : 0;
  s[tid] = v; __syncthreads();
  for (int off = 1; off < 256; off <<= 1){
    int t = (tid >= off) ? s[tid-off] : 0;
    __syncthreads();
    s[tid] += t;
    __syncthreads();
  }
  boff[tid] = s[tid] - v;
}

__global__ __launch_bounds__(256) void scan3_kernel(int* __restrict__ rs,
                                                    const int* __restrict__ boff,
                                                    int* __restrict__ cursor,
                                                    int Nn, int E_){
  int i = blockIdx.x*256 + threadIdx.x;
  if (i < Nn){
    int v = rs[i] + boff[i >> 9];
    rs[i] = v;
    cursor[i] = v;
  }
  if (i == 0) rs[Nn] = E_;
}

__global__ __launch_bounds__(256) void scatter_kernel(const int* __restrict__ dst,
                                                      const int* __restrict__ src,
                                                      int* __restrict__ cursor,
                                                      int2* __restrict__ spp, int E_){
  int e = blockIdx.x*256 + threadIdx.x;
  if (e < E_){
    int pos = atomicAdd(&cursor[dst[e]], 1);
    spp[pos] = make_int2(src[e], e);
  }
}

// ---------------- MLP W transpose + hi/lo bf16 split ----------------
__global__ __launch_bounds__(256) void trans_kernel(const void* __restrict__ W,
                                                    ushort* __restrict__ hi,
                                                    ushort* __restrict__ lo,
                                                    const int* __restrict__ flag){
  int bf = flag[0];
  int idx = blockIdx.x*256 + threadIdx.x;   // grid covers 3*16384 exactly
  int l = idx >> 14, rem = idx & 16383, k = rem >> 7, n = rem & 127;
  float w = ldf(W, idx, bf);
  ushort h = f2bf(w);
  int di = (l << 14) | (n << 7) | k;
  hi[di] = h;
  lo[di] = f2bf(w - bf2f(h));
}

// edge-W transpose: in ew[l][k(16)][n(128)] -> out [l][n][k(16)] hi/lo bf16
__global__ __launch_bounds__(256) void trans_edge_kernel(const void* __restrict__ W,
                                                         ushort* __restrict__ hi,
                                                         ushort* __restrict__ lo,
                                                         const int* __restrict__ flag){
  int bf = flag[0];
  int idx = blockIdx.x*256 + threadIdx.x;   // grid covers 3*2048 exactly
  int l = idx >> 11, rem = idx & 2047, k = rem >> 7, n = rem & 127;
  float w = ldf(W, idx, bf);
  ushort h = f2bf(w);
  int di = (l << 11) | (n << 4) | k;
  hi[di] = h;
  lo[di] = f2bf(w - bf2f(h));
}

// ---------------- edge gather-aggregate + PRE combine (MFMA e_emb) ----------------
// hpre[n] = (1+eps)*(x[n]+vn) + sum_{e:dst=n} relu(x[src]+vn + attr@W + b)
// one wave per 2 consecutive nodes; 16-edge MFMA tiles.
// A = [attr_hi ; attr_lo] (K halves), B1=[W_hi;W_hi], B2=[W_lo;W_lo]:
//   MFMA1+MFMA2 = (attr_hi+attr_lo)@(W_hi+W_lo) ~= fp32-exact attr@W.
template<bool FIRST>
__global__ __launch_bounds__(256) void edge_agg_kernel(
    const int2* __restrict__ spp, const int* __restrict__ rs,
    const void* __restrict__ eattr,
    const ushort* __restrict__ weHi, const ushort* __restrict__ weLo,  // [128][16] this layer
    const void* __restrict__ eb, const void* __restrict__ vn,
    const void* __restrict__ epsp, int layer,
    const void* __restrict__ xin, const float* __restrict__ xws,
    float* __restrict__ hpre, int Nn, const int* __restrict__ flag)
{
  int bf = flag[0];
  __shared__ float eemb[4][16][132];      // per-wave scratch (33 KB), no barriers needed
  int lane = threadIdx.x & 63, wvi = threadIdx.x >> 6;
  int m_ = lane & 15, q = lane >> 4;      // MFMA coords
  int d0 = lane << 1;
  // loop-invariant B-frags: B[k=q*8+j][n=m_] = w[(q&1)*8+j][ci*16+m_]
  short8 bW1[8], bW2[8];
  #pragma unroll
  for (int ci = 0; ci < 8; ci++){
    int c = ci*16 + m_;
    bW1[ci] = *(const short8*)(weHi + c*16 + (q&1)*8);
    bW2[ci] = *(const short8*)(weLo + c*16 + (q&1)*8);
  }
  f32x2 vn2, cv;
  vn2[0] = ldf(vn, (long)layer*128 + d0,     bf);
  vn2[1] = ldf(vn, (long)layer*128 + d0 + 1, bf);
  cv[0] = ldf(eb, (long)layer*128 + d0,     bf) + vn2[0];
  cv[1] = ldf(eb, (long)layer*128 + d0 + 1, bf) + vn2[1];
  float epsv = 1.f + ldf(epsp, layer, bf);
  const float* xp32 = FIRST ? (const float*)xin : xws;

  int n0 = (blockIdx.x*4 + wvi)*2;
  if (n0 >= Nn) return;
  int beg   = rs[n0];
  int split = rs[n0+1];
  int end   = (n0+2 <= Nn) ? rs[n0+2] : split;
  f32x2 accA = {0.f, 0.f}, accB = {0.f, 0.f};

  for (int ii = beg; ii < end; ii += 16){
    int2 ip = spp[imin(ii + m_, end - 1)];   // lanes m_, m_+16.. load same -> quads agree
    // ---- A-frag: attr[edge m_], elems (q&1)*8..+8; hi for q<2, lo for q>=2
    short8 afrag;
    if (bf){
      const ushort* ap = (const ushort*)eattr + (long)ip.y*16 + (q&1)*8;
      uint4 ua = *(const uint4*)ap;
      const ushort* us = (const ushort*)&ua;
      #pragma unroll
      for (int j = 0; j < 8; j++) afrag[j] = (q < 2) ? (short)us[j] : (short)0;
    } else {
      const float* ap = (const float*)eattr + (long)ip.y*16 + (q&1)*8;
      float4 f0 = *(const float4*)ap, f1 = *(const float4*)(ap+4);
      float av[8] = {f0.x,f0.y,f0.z,f0.w,f1.x,f1.y,f1.z,f1.w};
      #pragma unroll
      for (int j = 0; j < 8; j++){
        ushort h = f2bf(av[j]);
        afrag[j] = (q < 2) ? (short)h : (short)f2bf(av[j] - bf2f(h));
      }
    }
    // ---- e_emb via MFMA, write C to wave LDS
    #pragma unroll
    for (int ci = 0; ci < 8; ci++){
      f32x4 acc = {0.f,0.f,0.f,0.f};
      acc = __builtin_amdgcn_mfma_f32_16x16x32_bf16(afrag, bW1[ci], acc, 0, 0, 0);
      acc = __builtin_amdgcn_mfma_f32_16x16x32_bf16(afrag, bW2[ci], acc, 0, 0, 0);
      int c = ci*16 + m_;
      #pragma unroll
      for (int rg = 0; rg < 4; rg++) eemb[wvi][q*4+rg][c] = acc[rg];
    }
    // ---- per-edge: gather x[src], combine, masked accumulate
    #pragma unroll
    for (int j = 0; j < 16; j++){
      int gidx = ii + j;
      int sj = __shfl(ip.x, j);
      f32x2 xv;
      if (FIRST && bf){
        uint u = *(const uint*)((const ushort*)xin + (long)sj*D + d0);
        xv[0] = __uint_as_float(u << 16);
        xv[1] = __uint_as_float(u & 0xffff0000u);
      } else {
        xv = *(const f32x2*)(xp32 + (long)sj*D + d0);
      }
      f32x2 ee = *(const f32x2*)&eemb[wvi][j][d0];
      float r0 = fmaxf(cv[0] + xv[0] + ee[0], 0.f);
      float r1 = fmaxf(cv[1] + xv[1] + ee[1], 0.f);
      bool inA = gidx < split;
      bool inB = (!inA) && (gidx < end);
      accA[0] += inA ? r0 : 0.f;  accA[1] += inA ? r1 : 0.f;
      accB[0] += inB ? r0 : 0.f;  accB[1] += inB ? r1 : 0.f;
    }
  }
  // ---- PRE combine + store both rows
  f32x2 xn;
  if (FIRST && bf){
    uint u = *(const uint*)((const ushort*)xin + (long)n0*D + d0);
    xn[0] = __uint_as_float(u << 16);
    xn[1] = __uint_as_float(u & 0xffff0000u);
  } else {
    xn = *(const f32x2*)(xp32 + (long)n0*D + d0);
  }
  f32x2 hp;
  hp[0] = epsv*(xn[0] + vn2[0]) + accA[0];
  hp[1] = epsv*(xn[1] + vn2[1]) + accA[1];
  *(f32x2*)(hpre + (long)n0*D + d0) = hp;
  if (n0 + 1 < Nn){
    f32x2 xm;
    if (FIRST && bf){
      uint u = *(const uint*)((const ushort*)xin + (long)(n0+1)*D + d0);
      xm[0] = __uint_as_float(u << 16);
      xm[1] = __uint_as_float(u & 0xffff0000u);
    } else {
      xm = *(const f32x2*)(xp32 + (long)(n0+1)*D + d0);
    }
    f32x2 hq;
    hq[0] = epsv*(xm[0] + vn2[0]) + accB[0];
    hq[1] = epsv*(xm[1] + vn2[1]) + accB[1];
    *(f32x2*)(hpre + (long)(n0+1)*D + d0) = hq;
  }
}

// ---------------- fused node MLP: out = relu(h@W1+b1)@W2+b2 (MFMA hi/lo) ----------------
__global__ __launch_bounds__(256) void mlp_fused(
    const float* __restrict__ hpre,
    const ushort* __restrict__ w1hi, const ushort* __restrict__ w1lo,
    const ushort* __restrict__ w2hi, const ushort* __restrict__ w2lo,
    const void* __restrict__ b1v, const void* __restrict__ b2v, int layer,
    float* __restrict__ outp, int Nn, const int* __restrict__ flag)
{
  int bf = flag[0];
  __shared__ ushort sbuf[2][64][136];   // hi plane / lo plane; reused for packed h1
  __shared__ float bias1[D], bias2[D];
  int tid = threadIdx.x;
  if (tid < D){
    bias1[tid] = ldf(b1v, (long)layer*D + tid, bf);
    bias2[tid] = ldf(b2v, (long)layer*D + tid, bf);
  }
  int srow = tid >> 2, scb = (tid & 3) << 5;
  long r = (long)blockIdx.x*64 + srow;
  {
    float hv[32];
    if (r < Nn){
      const float* xp = hpre + r*D + scb;
      #pragma unroll
      for (int j = 0; j < 32; j++) hv[j] = xp[j];
    } else {
      #pragma unroll
      for (int j = 0; j < 32; j++) hv[j] = 0.f;
    }
    uint* rowHi = (uint*)&sbuf[0][srow][0];
    uint* rowLo = (uint*)&sbuf[1][srow][0];
    #pragma unroll
    for (int j2 = 0; j2 < 16; j2++){
      float v0 = hv[2*j2], v1 = hv[2*j2+1];
      ushort h0 = f2bf(v0), h1 = f2bf(v1);
      ushort l0 = f2bf(v0 - bf2f(h0)), l1 = f2bf(v1 - bf2f(h1));
      rowHi[(scb>>1) + j2] = (uint)h0 | ((uint)h1 << 16);
      rowLo[(scb>>1) + j2] = (uint)l0 | ((uint)l1 << 16);
    }
  }
  __syncthreads();

  int lane = tid & 63, wvi = tid >> 6;
  int m = lane & 15, kq = lane >> 4;
  int lr = wvi*16 + m;
  short8 aHi[4], aLo[4];
  #pragma unroll
  for (int ki = 0; ki < 4; ki++){
    aHi[ki] = *(const short8*)&sbuf[0][lr][ki*32 + kq*8];
    aLo[ki] = *(const short8*)&sbuf[1][lr][ki*32 + kq*8];
  }
  float h1[8][4];
  #pragma unroll
  for (int ci = 0; ci < 8; ci++){
    int c = ci*16 + m;
    f32x4 acc;
    float bv = bias1[c];
    acc[0] = bv; acc[1] = bv; acc[2] = bv; acc[3] = bv;
    const ushort* bp = w1hi + ((long)c << 7) + kq*8;
    #pragma unroll
    for (int ki = 0; ki < 4; ki++){
      short8 bfr = *(const short8*)(bp + ki*32);
      acc = __builtin_amdgcn_mfma_f32_16x16x32_bf16(aHi[ki], bfr, acc, 0, 0, 0);
      acc = __builtin_amdgcn_mfma_f32_16x16x32_bf16(aLo[ki], bfr, acc, 0, 0, 0);
    }
    if (!bf){
      const ushort* blp = w1lo + ((long)c << 7) + kq*8;
      #pragma unroll
      for (int ki = 0; ki < 4; ki++){
        short8 blr = *(const short8*)(blp + ki*32);
        acc = __builtin_amdgcn_mfma_f32_16x16x32_bf16(aHi[ki], blr, acc, 0, 0, 0);
      }
    }
    #pragma unroll
    for (int rg = 0; rg < 4; rg++) h1[ci][rg] = fmaxf(acc[rg], 0.f);
  }
  __syncthreads();
  uint* h1p = (uint*)&sbuf[0][0][0];
  #pragma unroll
  for (int ci = 0; ci < 8; ci++){
    int c = ci*16 + m;
    #pragma unroll
    for (int rg = 0; rg < 4; rg++){
      int rl = wvi*16 + kq*4 + rg;
      float v = h1[ci][rg];
      ushort hi_ = f2bf(v);
      ushort lo_ = f2bf(v - bf2f(hi_));
      h1p[rl*132 + c] = ((uint)hi_ << 16) | (uint)lo_;
    }
  }
  __syncthreads();
  #pragma unroll
  for (int ki = 0; ki < 4; ki++){
    const uint* up = h1p + lr*132 + ki*32 + kq*8;
    uint4 ua = *(const uint4*)up;
    uint4 ub = *(const uint4*)(up + 4);
    uint uu[8] = {ua.x,ua.y,ua.z,ua.w, ub.x,ub.y,ub.z,ub.w};
    short8 ah, al;
    #pragma unroll
    for (int t = 0; t < 8; t++){
      ah[t] = (short)(uu[t] >> 16);
      al[t] = (short)(uu[t] & 0xffffu);
    }
    aHi[ki] = ah; aLo[ki] = al;
  }
  long rowBase = (long)blockIdx.x*64 + wvi*16 + kq*4;
  #pragma unroll
  for (int ci = 0; ci < 8; ci++){
    int c = ci*16 + m;
    f32x4 acc;
    float bv = bias2[c];
    acc[0] = bv; acc[1] = bv; acc[2] = bv; acc[3] = bv;
    const ushort* bp = w2hi + ((long)c << 7) + kq*8;
    #pragma unroll
    for (int ki = 0; ki < 4; ki++){
      short8 bfr = *(const short8*)(bp + ki*32);
      acc = __builtin_amdgcn_mfma_f32_16x16x32_bf16(aHi[ki], bfr, acc, 0, 0, 0);
      acc = __builtin_amdgcn_mfma_f32_16x16x32_bf16(aLo[ki], bfr, acc, 0, 0, 0);
    }
    if (!bf){
      const ushort* blp = w2lo + ((long)c << 7) + kq*8;
      #pragma unroll
      for (int ki = 0; ki < 4; ki++){
        short8 blr = *(const short8*)(blp + ki*32);
        acc = __builtin_amdgcn_mfma_f32_16x16x32_bf16(aHi[ki], blr, acc, 0, 0, 0);
      }
    }
    #pragma unroll
    for (int rg = 0; rg < 4; rg++){
      long orow = rowBase + rg;
      if (orow < Nn) outp[orow*D + c] = acc[rg];
    }
  }
}

// ---------------- segment pool (batch is sorted), 4-way row split ----------------
__global__ __launch_bounds__(512) void pool_kernel(
    const float* __restrict__ x, const int* __restrict__ batch,
    int Nn, float* __restrict__ g, int colOff)
{
  __shared__ float part[3][128];
  int b = blockIdx.x;
  int c = threadIdx.x & 127, h = threadIdx.x >> 7;   // h in 0..3
  int lo = 0, hi = Nn;
  while (lo < hi){ int mid = (lo+hi)>>1; if (batch[mid] <  b) lo = mid+1; else hi = mid; }
  int start = lo;
  hi = Nn;
  while (lo < hi){ int mid = (lo+hi)>>1; if (batch[mid] <= b) lo = mid+1; else hi = mid; }
  int end = lo;
  float acc = 0.f;
  for (int r = start + h; r < end; r += 4) acc += x[(long)r*D + c];
  if (h) part[h-1][c] = acc;
  __syncthreads();
  if (!h) g[(long)b*384 + colOff + c] = acc + part[0][c] + part[1][c] + part[2][c];
}

// ---------------- head: Linear->LN->ReLU x2 -> Linear ----------------
__global__ __launch_bounds__(256) void head_kernel(
    const float* __restrict__ g,
    const void* __restrict__ w1, const void* __restrict__ b1,
    const void* __restrict__ g1, const void* __restrict__ be1,
    const void* __restrict__ w2, const void* __restrict__ b2,
    const void* __restrict__ g2, const void* __restrict__ be2,
    const void* __restrict__ ow, const void* __restrict__ ob,
    void* __restrict__ outp, const int* __restrict__ flag)
{
  int bf = flag[0];
  __shared__ float grow[384];
  __shared__ float h1[256];
  __shared__ float h2[128];
  __shared__ float redA[4], redB[4], stats[2];
  int b = blockIdx.x, tid = threadIdx.x;
  for (int i = tid; i < 384; i += 256) grow[i] = g[(long)b*384 + i];
  __syncthreads();
  float v = ldf(b1, tid, bf);
  for (int k = 0; k < 384; k++) v += grow[k] * ldf(w1, (long)k*256 + tid, bf);
  float s = v, s2 = v*v;
  for (int o = 32; o; o >>= 1){ s += __shfl_down(s,o); s2 += __shfl_down(s2,o); }
  if ((tid & 63) == 0){ redA[tid>>6] = s; redB[tid>>6] = s2; }
  __syncthreads();
  if (tid == 0){
    float S = redA[0]+redA[1]+redA[2]+redA[3];
    float S2 = redB[0]+redB[1]+redB[2]+redB[3];
    float mu = S / 256.f;
    stats[0] = mu; stats[1] = rsqrtf(S2/256.f - mu*mu + 1e-5f);
  }
  __syncthreads();
  float y = (v - stats[0]) * stats[1] * ldf(g1, tid, bf) + ldf(be1, tid, bf);
  h1[tid] = fmaxf(y, 0.f);
  __syncthreads();
  float v2 = 0.f;
  if (tid < 128){
    v2 = ldf(b2, tid, bf);
    for (int k = 0; k < 256; k++) v2 += h1[k] * ldf(w2, (long)k*128 + tid, bf);
  }
  float t = (tid < 128) ? v2 : 0.f;
  s = t; s2 = t*t;
  for (int o = 32; o; o >>= 1){ s += __shfl_down(s,o); s2 += __shfl_down(s2,o); }
  if ((tid & 63) == 0){ redA[tid>>6] = s; redB[tid>>6] = s2; }
  __syncthreads();
  if (tid == 0){
    float S = redA[0]+redA[1]+redA[2]+redA[3];
    float S2 = redB[0]+redB[1]+redB[2]+redB[3];
    float mu = S / 128.f;
    stats[0] = mu; stats[1] = rsqrtf(S2/128.f - mu*mu + 1e-5f);
  }
  __syncthreads();
  if (tid < 128){
    float y2 = (v2 - stats[0]) * stats[1] * ldf(g2, tid, bf) + ldf(be2, tid, bf);
    h2[tid] = fmaxf(y2, 0.f);
  }
  __syncthreads();
  float p = (tid < 128) ? h2[tid] * ldf(ow, tid, bf) : 0.f;
  s = p;
  for (int o = 32; o; o >>= 1) s += __shfl_down(s, o);
  if ((tid & 63) == 0) redA[tid>>6] = s;
  __syncthreads();
  if (tid == 0){
    float r = redA[0]+redA[1]+redA[2]+redA[3] + ldf(ob, 0, bf);
    if (bf) ((ushort*)outp)[b] = f2bf(r);
    else    ((float*)outp)[b]  = r;
  }
}

extern "C" void kernel_launch(void* const* d_in, const int* in_sizes, int n_in,
                              void* d_out, int out_size, void* d_ws, size_t ws_size,
                              hipStream_t stream)
{
  const void* x_in  = d_in[0];
  const int*  eidx  = (const int*)d_in[1];
  const void* eattr = d_in[2];
  const int*  batch = (const int*)d_in[3];
  const void* vn    = d_in[4];
  const void* ew    = d_in[5];
  const void* eb    = d_in[6];
  const void* epsp  = d_in[7];
  const void* w1p   = d_in[8];
  const void* b1p   = d_in[9];
  const void* w2p   = d_in[10];
  const void* b2p   = d_in[11];
  const void* lw1   = d_in[12];
  const void* lb1   = d_in[13];
  const void* ln1g  = d_in[14];
  const void* ln1b  = d_in[15];
  const void* lw2   = d_in[16];
  const void* lb2   = d_in[17];
  const void* ln2g  = d_in[18];
  const void* ln2b  = d_in[19];
  const void* owp   = d_in[20];
  const void* obp   = d_in[21];

  int Nn = in_sizes[0] / D;     // 50000
  int Ee = in_sizes[1] / 2;     // 600000
  int Gg = out_size;            // 512
  const int* srcp = eidx;
  const int* dstp = eidx + Ee;

  float*  A     = (float*)d_ws;                 // hpre scratch
  float*  B     = A + (size_t)Nn*D;             // layer outs (ping)
  float*  C     = B + (size_t)Nn*D;             // layer outs (pong)
  float*  gbuf  = C + (size_t)Nn*D;
  ushort* wT1hi = (ushort*)(gbuf + (size_t)Gg*384);
  ushort* wT1lo = wT1hi + 3*D*D;
  ushort* wT2hi = wT1lo + 3*D*D;
  ushort* wT2lo = wT2hi + 3*D*D;
  ushort* weHi  = wT2lo + 3*D*D;      // [3][128][16]
  ushort* weLo  = weHi + 3*128*16;
  int*    flag  = (int*)(weLo + 3*128*16);
  int*    deg     = flag + 1;
  int*    rs      = deg + Nn;        // N+1
  int*    cursor  = rs + Nn + 1;
  int*    bsum    = cursor + Nn;
  int*    boff    = bsum + 256;
  int2*   spp     = (int2*)(boff + 256);

  detect_kernel<<<1,256,0,stream>>>((const uint*)x_in, flag);

  // CSR build (once; dst/src invariant across layers)
  int NB = (Nn + 511) / 512;
  hipMemsetAsync(deg, 0, (size_t)Nn*sizeof(int), stream);
  hist_kernel<<<(Ee+255)/256,256,0,stream>>>(dstp, deg, Ee);
  scan1_kernel<<<NB,256,0,stream>>>(deg, rs, bsum, Nn);
  scan2_kernel<<<1,256,0,stream>>>(bsum, boff, NB);
  scan3_kernel<<<(Nn+255)/256,256,0,stream>>>(rs, boff, cursor, Nn, Ee);
  scatter_kernel<<<(Ee+255)/256,256,0,stream>>>(dstp, srcp, cursor, spp, Ee);

  trans_kernel<<<192,256,0,stream>>>(w1p, wT1hi, wT1lo, flag);
  trans_kernel<<<192,256,0,stream>>>(w2p, wT2hi, wT2lo, flag);
  trans_edge_kernel<<<24,256,0,stream>>>(ew, weHi, weLo, flag);

  int mlpGrid  = (Nn + 63) / 64;    // 782
  int edgeGrid = (Nn + 7) / 8;      // 6250 (one wave per 2 nodes, no stride loop)
  float* xcur = nullptr;
  for (int i = 0; i < 3; i++){
    float* out = (i == 1) ? C : B;    // L0->B, L1->C, L2->B
    if (i == 0)
      edge_agg_kernel<true ><<<edgeGrid,256,0,stream>>>(spp, rs, eattr,
                                                        weHi + (size_t)i*2048, weLo + (size_t)i*2048,
                                                        eb, vn, epsp, i, x_in, nullptr, A, Nn, flag);
    else
      edge_agg_kernel<false><<<edgeGrid,256,0,stream>>>(spp, rs, eattr,
                                                        weHi + (size_t)i*2048, weLo + (size_t)i*2048,
                                                        eb, vn, epsp, i, nullptr, xcur, A, Nn, flag);
    mlp_fused<<<mlpGrid,256,0,stream>>>(A,
                                        wT1hi + (size_t)i*D*D, wT1lo + (size_t)i*D*D,
                                        wT2hi + (size_t)i*D*D, wT2lo + (size_t)i*D*D,
                                        b1p, b2p, i, out, Nn, flag);
    pool_kernel<<<Gg,512,0,stream>>>(out, batch, Nn, gbuf, i*D);
    xcur = out;
  }
  head_kernel<<<Gg,256,0,stream>>>(gbuf, lw1, lb1, ln1g, ln1b,
                                   lw2, lb2, ln2g, ln2b, owp, obp, d_out, flag);
}

// Round 8
// 798.454 us; speedup vs baseline: 1.1202x; 1.1202x over previous
//
#include <hip/hip_runtime.h>

typedef unsigned int uint;
typedef unsigned short ushort;
typedef __attribute__((ext_vector_type(8))) short short8;
typedef __attribute__((ext_vector_type(4))) float f32x4;
typedef __attribute__((ext_vector_type(2))) float f32x2;

#define D 128

__device__ __forceinline__ float bf2f(ushort h){ return __uint_as_float(((uint)h)<<16); }
__device__ __forceinline__ ushort f2bf(float f){
  uint u = __float_as_uint(f);
  u += 0x7fff + ((u >> 16) & 1);   // RNE
  return (ushort)(u >> 16);
}
__device__ __forceinline__ float ldf(const void* p, long i, int bf){
  return bf ? bf2f(((const ushort*)p)[i]) : ((const float*)p)[i];
}
__device__ __forceinline__ int imin(int a, int b){ return a < b ? a : b; }

// ---------------- dtype detection ----------------
__global__ __launch_bounds__(256) void detect_kernel(const uint* __restrict__ xw,
                                                     int* __restrict__ flag){
  __shared__ int cnt;
  if (threadIdx.x == 0) cnt = 0;
  __syncthreads();
  uint w = xw[threadIdx.x];
  int ef = (int)((w >> 7) & 0xffu);
  if (ef >= 90 && ef <= 142) atomicAdd(&cnt, 1);
  __syncthreads();
  if (threadIdx.x == 0) flag[0] = (cnt >= 128) ? 1 : 0;
}

// ---------------- CSR build (dst/src are layer-invariant) ----------------
__global__ __launch_bounds__(256) void hist_kernel(const int* __restrict__ dst,
                                                   int* __restrict__ deg, int E_){
  int e = blockIdx.x*256 + threadIdx.x;
  if (e < E_) atomicAdd(&deg[dst[e]], 1);
}

__global__ __launch_bounds__(256) void scan1_kernel(const int* __restrict__ deg,
                                                    int* __restrict__ rs,
                                                    int* __restrict__ bsum, int Nn){
  __shared__ int s[256];
  int tid = threadIdx.x;
  int base = blockIdx.x*512;
  int i0 = base + 2*tid, i1 = i0 + 1;
  int a = (i0 < Nn) ? deg[i0] : 0;
  int b = (i1 < Nn) ? deg[i1] : 0;
  int p = a + b;
  s[tid] = p; __syncthreads();
  for (int off = 1; off < 256; off <<= 1){
    int t = (tid >= off) ? s[tid-off] : 0;
    __syncthreads();
    s[tid] += t;
    __syncthreads();
  }
  int ex = s[tid] - p;
  if (i0 < Nn) rs[i0] = ex;
  if (i1 < Nn) rs[i1] = ex + a;
  if (tid == 255) bsum[blockIdx.x] = s[255];
}

__global__ __launch_bounds__(256) void scan2_kernel(const int* __restrict__ bsum,
                                                    int* __restrict__ boff, int NB){
  __shared__ int s[256];
  int tid = threadIdx.x;
  int v = (tid < NB) ? bsum[tid] : 0;
  s[tid] = v; __syncthreads();
  for (int off = 1; off < 256; off <<= 1){
    int t = (tid >= off) ? s[tid-off] : 0;
    __syncthreads();
    s[tid] += t;
    __syncthreads();
  }
  boff[tid] = s[tid] - v;
}

__global__ __launch_bounds__(256) void scan3_kernel(int* __restrict__ rs,
                                                    const int* __restrict__ boff,
                                                    int* __restrict__ cursor,
                                                    int Nn, int E_){
  int i = blockIdx.x*256 + threadIdx.x;
  if (i < Nn){
    int v = rs[i] + boff[i >> 9];
    rs[i] = v;
    cursor[i] = v;
  }
  if (i == 0) rs[Nn] = E_;
}

__global__ __launch_bounds__(256) void scatter_kernel(const int* __restrict__ dst,
                                                      const int* __restrict__ src,
                                                      int* __restrict__ cursor,
                                                      int2* __restrict__ spp, int E_){
  int e = blockIdx.x*256 + threadIdx.x;
  if (e < E_){
    int pos = atomicAdd(&cursor[dst[e]], 1);
    spp[pos] = make_int2(src[e], e);
  }
}

// ---------------- MLP W transpose + hi/lo bf16 split ----------------
__global__ __launch_bounds__(256) void trans_kernel(const void* __restrict__ W,
                                                    ushort* __restrict__ hi,
                                                    ushort* __restrict__ lo,
                                                    const int* __restrict__ flag){
  int bf = flag[0];
  int idx = blockIdx.x*256 + threadIdx.x;   // grid covers 3*16384 exactly
  int l = idx >> 14, rem = idx & 16383, k = rem >> 7, n = rem & 127;
  float w = ldf(W, idx, bf);
  ushort h = f2bf(w);
  int di = (l << 14) | (n << 7) | k;
  hi[di] = h;
  lo[di] = f2bf(w - bf2f(h));
}

// edge-W transpose: in ew[l][k(16)][n(128)] -> out [l][n][k(16)] hi/lo bf16
__global__ __launch_bounds__(256) void trans_edge_kernel(const void* __restrict__ W,
                                                         ushort* __restrict__ hi,
                                                         ushort* __restrict__ lo,
                                                         const int* __restrict__ flag){
  int bf = flag[0];
  int idx = blockIdx.x*256 + threadIdx.x;   // grid covers 3*2048 exactly
  int l = idx >> 11, rem = idx & 2047, k = rem >> 7, n = rem & 127;
  float w = ldf(W, idx, bf);
  ushort h = f2bf(w);
  int di = (l << 11) | (n << 4) | k;
  hi[di] = h;
  lo[di] = f2bf(w - bf2f(h));
}

// ---------------- edge gather-aggregate + PRE combine (pipelined MFMA e_emb) ----------------
// hpre[n] = (1+eps)*(x[n]+vn) + sum_{e:dst=n} relu(x[src]+vn + attr@W + b)
// one wave per 2 consecutive nodes (grid-stride); 16-edge MFMA tiles;
// spp prefetched one chunk ahead; x-gathers issued in 8-edge batches.
template<bool FIRST>
__global__ __launch_bounds__(256) void edge_agg_kernel(
    const int2* __restrict__ spp, const int* __restrict__ rs,
    const void* __restrict__ eattr,
    const ushort* __restrict__ weHi, const ushort* __restrict__ weLo,  // [128][16] this layer
    const void* __restrict__ eb, const void* __restrict__ vn,
    const void* __restrict__ epsp, int layer,
    const void* __restrict__ xin, const float* __restrict__ xws,
    float* __restrict__ hpre, int Nn, const int* __restrict__ flag)
{
  int bf = flag[0];
  __shared__ float eemb[4][16][132];      // per-wave scratch, +4 pad vs banks
  int lane = threadIdx.x & 63, wvi = threadIdx.x >> 6;
  int m_ = lane & 15, q = lane >> 4;      // MFMA coords
  int d0 = lane << 1;
  // loop-invariant B-frags
  short8 bW1[8], bW2[8];
  #pragma unroll
  for (int ci = 0; ci < 8; ci++){
    int c = ci*16 + m_;
    bW1[ci] = *(const short8*)(weHi + c*16 + (q&1)*8);
    bW2[ci] = *(const short8*)(weLo + c*16 + (q&1)*8);
  }
  f32x2 vn2, cv;
  vn2[0] = ldf(vn, (long)layer*128 + d0,     bf);
  vn2[1] = ldf(vn, (long)layer*128 + d0 + 1, bf);
  cv[0] = ldf(eb, (long)layer*128 + d0,     bf) + vn2[0];
  cv[1] = ldf(eb, (long)layer*128 + d0 + 1, bf) + vn2[1];
  float epsv = 1.f + ldf(epsp, layer, bf);
  const float* xp32 = FIRST ? (const float*)xin : xws;

  for (int n0 = (blockIdx.x*4 + wvi)*2; n0 < Nn; n0 += gridDim.x*8){
    int beg   = rs[n0];
    int split = rs[n0+1];
    int end   = (n0+2 <= Nn) ? rs[n0+2] : split;
    f32x2 accA = {0.f, 0.f}, accB = {0.f, 0.f};
    int2 ip = (beg < end) ? spp[imin(beg + m_, end - 1)] : make_int2(0, 0);

    for (int ii = beg; ii < end; ii += 16){
      // ---- attr load for current chunk (depends on ip, fetched last iter)
      uint4 ua; float4 f0, f1;
      {
        long arow = (long)ip.y * 16 + (q & 1) * 8;
        if (bf){
          ua = *(const uint4*)((const ushort*)eattr + arow);
        } else {
          const float* ap = (const float*)eattr + arow;
          f0 = *(const float4*)ap; f1 = *(const float4*)(ap + 4);
        }
      }
      // ---- prefetch next chunk's spp
      bool more = (ii + 16) < end;
      int2 ipn = more ? spp[imin(ii + 16 + m_, end - 1)] : ip;
      // ---- build A-frag (hi for q<2, lo for q>=2)
      short8 afrag;
      if (bf){
        const ushort* us = (const ushort*)&ua;
        #pragma unroll
        for (int j = 0; j < 8; j++) afrag[j] = (q < 2) ? (short)us[j] : (short)0;
      } else {
        float av[8] = {f0.x,f0.y,f0.z,f0.w,f1.x,f1.y,f1.z,f1.w};
        #pragma unroll
        for (int j = 0; j < 8; j++){
          ushort h = f2bf(av[j]);
          afrag[j] = (q < 2) ? (short)h : (short)f2bf(av[j] - bf2f(h));
        }
      }
      // ---- e_emb via MFMA, C -> wave LDS
      #pragma unroll
      for (int ci = 0; ci < 8; ci++){
        f32x4 acc = {0.f,0.f,0.f,0.f};
        acc = __builtin_amdgcn_mfma_f32_16x16x32_bf16(afrag, bW1[ci], acc, 0, 0, 0);
        acc = __builtin_amdgcn_mfma_f32_16x16x32_bf16(afrag, bW2[ci], acc, 0, 0, 0);
        int c = ci*16 + m_;
        #pragma unroll
        for (int rg = 0; rg < 4; rg++) eemb[wvi][q*4+rg][c] = acc[rg];
      }
      // ---- combine in 8-edge batches: issue gathers first, then reduce
      #pragma unroll
      for (int jb = 0; jb < 2; jb++){
        int ss[8];
        #pragma unroll
        for (int j = 0; j < 8; j++) ss[j] = __shfl(ip.x, jb*8 + j);
        f32x2 xv[8];
        #pragma unroll
        for (int j = 0; j < 8; j++){
          if (FIRST && bf){
            uint u = *(const uint*)((const ushort*)xin + (long)ss[j]*D + d0);
            xv[j][0] = __uint_as_float(u << 16);
            xv[j][1] = __uint_as_float(u & 0xffff0000u);
          } else {
            xv[j] = *(const f32x2*)(xp32 + (long)ss[j]*D + d0);
          }
        }
        #pragma unroll
        for (int j = 0; j < 8; j++){
          int gidx = ii + jb*8 + j;
          f32x2 ee = *(const f32x2*)&eemb[wvi][jb*8 + j][d0];
          float r0 = fmaxf(cv[0] + xv[j][0] + ee[0], 0.f);
          float r1 = fmaxf(cv[1] + xv[j][1] + ee[1], 0.f);
          bool inA = gidx < split;
          bool inB = (!inA) && (gidx < end);
          accA[0] += inA ? r0 : 0.f;  accA[1] += inA ? r1 : 0.f;
          accB[0] += inB ? r0 : 0.f;  accB[1] += inB ? r1 : 0.f;
        }
      }
      ip = ipn;
    }
    // ---- PRE combine + store both rows
    f32x2 xn;
    if (FIRST && bf){
      uint u = *(const uint*)((const ushort*)xin + (long)n0*D + d0);
      xn[0] = __uint_as_float(u << 16);
      xn[1] = __uint_as_float(u & 0xffff0000u);
    } else {
      xn = *(const f32x2*)(xp32 + (long)n0*D + d0);
    }
    f32x2 hp;
    hp[0] = epsv*(xn[0] + vn2[0]) + accA[0];
    hp[1] = epsv*(xn[1] + vn2[1]) + accA[1];
    *(f32x2*)(hpre + (long)n0*D + d0) = hp;
    if (n0 + 1 < Nn){
      f32x2 xm;
      if (FIRST && bf){
        uint u = *(const uint*)((const ushort*)xin + (long)(n0+1)*D + d0);
        xm[0] = __uint_as_float(u << 16);
        xm[1] = __uint_as_float(u & 0xffff0000u);
      } else {
        xm = *(const f32x2*)(xp32 + (long)(n0+1)*D + d0);
      }
      f32x2 hq;
      hq[0] = epsv*(xm[0] + vn2[0]) + accB[0];
      hq[1] = epsv*(xm[1] + vn2[1]) + accB[1];
      *(f32x2*)(hpre + (long)(n0+1)*D + d0) = hq;
    }
  }
}

// ---------------- fused node MLP: out = relu(h@W1+b1)@W2+b2 (MFMA hi/lo) ----------------
__global__ __launch_bounds__(256) void mlp_fused(
    const float* __restrict__ hpre,
    const ushort* __restrict__ w1hi, const ushort* __restrict__ w1lo,
    const ushort* __restrict__ w2hi, const ushort* __restrict__ w2lo,
    const void* __restrict__ b1v, const void* __restrict__ b2v, int layer,
    float* __restrict__ outp, int Nn, const int* __restrict__ flag)
{
  int bf = flag[0];
  __shared__ ushort sbuf[2][64][136];   // hi plane / lo plane; reused for packed h1
  __shared__ float bias1[D], bias2[D];
  int tid = threadIdx.x;
  if (tid < D){
    bias1[tid] = ldf(b1v, (long)layer*D + tid, bf);
    bias2[tid] = ldf(b2v, (long)layer*D + tid, bf);
  }
  int srow = tid >> 2, scb = (tid & 3) << 5;
  long r = (long)blockIdx.x*64 + srow;
  {
    float hv[32];
    if (r < Nn){
      const float* xp = hpre + r*D + scb;
      #pragma unroll
      for (int j = 0; j < 32; j++) hv[j] = xp[j];
    } else {
      #pragma unroll
      for (int j = 0; j < 32; j++) hv[j] = 0.f;
    }
    uint* rowHi = (uint*)&sbuf[0][srow][0];
    uint* rowLo = (uint*)&sbuf[1][srow][0];
    #pragma unroll
    for (int j2 = 0; j2 < 16; j2++){
      float v0 = hv[2*j2], v1 = hv[2*j2+1];
      ushort h0 = f2bf(v0), h1 = f2bf(v1);
      ushort l0 = f2bf(v0 - bf2f(h0)), l1 = f2bf(v1 - bf2f(h1));
      rowHi[(scb>>1) + j2] = (uint)h0 | ((uint)h1 << 16);
      rowLo[(scb>>1) + j2] = (uint)l0 | ((uint)l1 << 16);
    }
  }
  __syncthreads();

  int lane = tid & 63, wvi = tid >> 6;
  int m = lane & 15, kq = lane >> 4;
  int lr = wvi*16 + m;
  short8 aHi[4], aLo[4];
  #pragma unroll
  for (int ki = 0; ki < 4; ki++){
    aHi[ki] = *(const short8*)&sbuf[0][lr][ki*32 + kq*8];
    aLo[ki] = *(const short8*)&sbuf[1][lr][ki*32 + kq*8];
  }
  float h1[8][4];
  #pragma unroll
  for (int ci = 0; ci < 8; ci++){
    int c = ci*16 + m;
    f32x4 acc;
    float bv = bias1[c];
    acc[0] = bv; acc[1] = bv; acc[2] = bv; acc[3] = bv;
    const ushort* bp = w1hi + ((long)c << 7) + kq*8;
    #pragma unroll
    for (int ki = 0; ki < 4; ki++){
      short8 bfr = *(const short8*)(bp + ki*32);
      acc = __builtin_amdgcn_mfma_f32_16x16x32_bf16(aHi[ki], bfr, acc, 0, 0, 0);
      acc = __builtin_amdgcn_mfma_f32_16x16x32_bf16(aLo[ki], bfr, acc, 0, 0, 0);
    }
    if (!bf){
      const ushort* blp = w1lo + ((long)c << 7) + kq*8;
      #pragma unroll
      for (int ki = 0; ki < 4; ki++){
        short8 blr = *(const short8*)(blp + ki*32);
        acc = __builtin_amdgcn_mfma_f32_16x16x32_bf16(aHi[ki], blr, acc, 0, 0, 0);
      }
    }
    #pragma unroll
    for (int rg = 0; rg < 4; rg++) h1[ci][rg] = fmaxf(acc[rg], 0.f);
  }
  __syncthreads();
  uint* h1p = (uint*)&sbuf[0][0][0];
  #pragma unroll
  for (int ci = 0; ci < 8; ci++){
    int c = ci*16 + m;
    #pragma unroll
    for (int rg = 0; rg < 4; rg++){
      int rl = wvi*16 + kq*4 + rg;
      float v = h1[ci][rg];
      ushort hi_ = f2bf(v);
      ushort lo_ = f2bf(v - bf2f(hi_));
      h1p[rl*132 + c] = ((uint)hi_ << 16) | (uint)lo_;
    }
  }
  __syncthreads();
  #pragma unroll
  for (int ki = 0; ki < 4; ki++){
    const uint* up = h1p + lr*132 + ki*32 + kq*8;
    uint4 ua = *(const uint4*)up;
    uint4 ub = *(const uint4*)(up + 4);
    uint uu[8] = {ua.x,ua.y,ua.z,ua.w, ub.x,ub.y,ub.z,ub.w};
    short8 ah, al;
    #pragma unroll
    for (int t = 0; t < 8; t++){
      ah[t] = (short)(uu[t] >> 16);
      al[t] = (short)(uu[t] & 0xffffu);
    }
    aHi[ki] = ah; aLo[ki] = al;
  }
  long rowBase = (long)blockIdx.x*64 + wvi*16 + kq*4;
  #pragma unroll
  for (int ci = 0; ci < 8; ci++){
    int c = ci*16 + m;
    f32x4 acc;
    float bv = bias2[c];
    acc[0] = bv; acc[1] = bv; acc[2] = bv; acc[3] = bv;
    const ushort* bp = w2hi + ((long)c << 7) + kq*8;
    #pragma unroll
    for (int ki = 0; ki < 4; ki++){
      short8 bfr = *(const short8*)(bp + ki*32);
      acc = __builtin_amdgcn_mfma_f32_16x16x32_bf16(aHi[ki], bfr, acc, 0, 0, 0);
      acc = __builtin_amdgcn_mfma_f32_16x16x32_bf16(aLo[ki], bfr, acc, 0, 0, 0);
    }
    if (!bf){
      const ushort* blp = w2lo + ((long)c << 7) + kq*8;
      #pragma unroll
      for (int ki = 0; ki < 4; ki++){
        short8 blr = *(const short8*)(blp + ki*32);
        acc = __builtin_amdgcn_mfma_f32_16x16x32_bf16(aHi[ki], blr, acc, 0, 0, 0);
      }
    }
    #pragma unroll
    for (int rg = 0; rg < 4; rg++){
      long orow = rowBase + rg;
      if (orow < Nn) outp[orow*D + c] = acc[rg];
    }
  }
}

// ---------------- segment pool (batch is sorted), 4-way row split ----------------
__global__ __launch_bounds__(512) void pool_kernel(
    const float* __restrict__ x, const int* __restrict__ batch,
    int Nn, float* __restrict__ g, int colOff)
{
  __shared__ float part[3][128];
  int b = blockIdx.x;
  int c = threadIdx.x & 127, h = threadIdx.x >> 7;   // h in 0..3
  int lo = 0, hi = Nn;
  while (lo < hi){ int mid = (lo+hi)>>1; if (batch[mid] <  b) lo = mid+1; else hi = mid; }
  int start = lo;
  hi = Nn;
  while (lo < hi){ int mid = (lo+hi)>>1; if (batch[mid] <= b) lo = mid+1; else hi = mid; }
  int end = lo;
  float acc = 0.f;
  for (int r = start + h; r < end; r += 4) acc += x[(long)r*D + c];
  if (h) part[h-1][c] = acc;
  __syncthreads();
  if (!h) g[(long)b*384 + colOff + c] = acc + part[0][c] + part[1][c] + part[2][c];
}

// ---------------- head: Linear->LN->ReLU x2 -> Linear ----------------
__global__ __launch_bounds__(256) void head_kernel(
    const float* __restrict__ g,
    const void* __restrict__ w1, const void* __restrict__ b1,
    const void* __restrict__ g1, const void* __restrict__ be1,
    const void* __restrict__ w2, const void* __restrict__ b2,
    const void* __restrict__ g2, const void* __restrict__ be2,
    const void* __restrict__ ow, const void* __restrict__ ob,
    void* __restrict__ outp, const int* __restrict__ flag)
{
  int bf = flag[0];
  __shared__ float grow[384];
  __shared__ float h1[256];
  __shared__ float h2[128];
  __shared__ float redA[4], redB[4], stats[2];
  int b = blockIdx.x, tid = threadIdx.x;
  for (int i = tid; i < 384; i += 256) grow[i] = g[(long)b*384 + i];
  __syncthreads();
  float v = ldf(b1, tid, bf);
  for (int k = 0; k < 384; k++) v += grow[k] * ldf(w1, (long)k*256 + tid, bf);
  float s = v, s2 = v*v;
  for (int o = 32; o; o >>= 1){ s += __shfl_down(s,o); s2 += __shfl_down(s2,o); }
  if ((tid & 63) == 0){ redA[tid>>6] = s; redB[tid>>6] = s2; }
  __syncthreads();
  if (tid == 0){
    float S = redA[0]+redA[1]+redA[2]+redA[3];
    float S2 = redB[0]+redB[1]+redB[2]+redB[3];
    float mu = S / 256.f;
    stats[0] = mu; stats[1] = rsqrtf(S2/256.f - mu*mu + 1e-5f);
  }
  __syncthreads();
  float y = (v - stats[0]) * stats[1] * ldf(g1, tid, bf) + ldf(be1, tid, bf);
  h1[tid] = fmaxf(y, 0.f);
  __syncthreads();
  float v2 = 0.f;
  if (tid < 128){
    v2 = ldf(b2, tid, bf);
    for (int k = 0; k < 256; k++) v2 += h1[k] * ldf(w2, (long)k*128 + tid, bf);
  }
  float t = (tid < 128) ? v2 : 0.f;
  s = t; s2 = t*t;
  for (int o = 32; o; o >>= 1){ s += __shfl_down(s,o); s2 += __shfl_down(s2,o); }
  if ((tid & 63) == 0){ redA[tid>>6] = s; redB[tid>>6] = s2; }
  __syncthreads();
  if (tid == 0){
    float S = redA[0]+redA[1]+redA[2]+redA[3];
    float S2 = redB[0]+redB[1]+redB[2]+redB[3];
    float mu = S / 128.f;
    stats[0] = mu; stats[1] = rsqrtf(S2/128.f - mu*mu + 1e-5f);
  }
  __syncthreads();
  if (tid < 128){
    float y2 = (v2 - stats[0]) * stats[1] * ldf(g2, tid, bf) + ldf(be2, tid, bf);
    h2[tid] = fmaxf(y2, 0.f);
  }
  __syncthreads();
  float p = (tid < 128) ? h2[tid] * ldf(ow, tid, bf) : 0.f;
  s = p;
  for (int o = 32; o; o >>= 1) s += __shfl_down(s, o);
  if ((tid & 63) == 0) redA[tid>>6] = s;
  __syncthreads();
  if (tid == 0){
    float r = redA[0]+redA[1]+redA[2]+redA[3] + ldf(ob, 0, bf);
    if (bf) ((ushort*)outp)[b] = f2bf(r);
    else    ((float*)outp)[b]  = r;
  }
}

extern "C" void kernel_launch(void* const* d_in, const int* in_sizes, int n_in,
                              void* d_out, int out_size, void* d_ws, size_t ws_size,
                              hipStream_t stream)
{
  const void* x_in  = d_in[0];
  const int*  eidx  = (const int*)d_in[1];
  const void* eattr = d_in[2];
  const int*  batch = (const int*)d_in[3];
  const void* vn    = d_in[4];
  const void* ew    = d_in[5];
  const void* eb    = d_in[6];
  const void* epsp  = d_in[7];
  const void* w1p   = d_in[8];
  const void* b1p   = d_in[9];
  const void* w2p   = d_in[10];
  const void* b2p   = d_in[11];
  const void* lw1   = d_in[12];
  const void* lb1   = d_in[13];
  const void* ln1g  = d_in[14];
  const void* ln1b  = d_in[15];
  const void* lw2   = d_in[16];
  const void* lb2   = d_in[17];
  const void* ln2g  = d_in[18];
  const void* ln2b  = d_in[19];
  const void* owp   = d_in[20];
  const void* obp   = d_in[21];

  int Nn = in_sizes[0] / D;     // 50000
  int Ee = in_sizes[1] / 2;     // 600000
  int Gg = out_size;            // 512
  const int* srcp = eidx;
  const int* dstp = eidx + Ee;

  float*  A     = (float*)d_ws;                 // hpre scratch
  float*  B     = A + (size_t)Nn*D;             // layer outs (ping)
  float*  C     = B + (size_t)Nn*D;             // layer outs (pong)
  float*  gbuf  = C + (size_t)Nn*D;
  ushort* wT1hi = (ushort*)(gbuf + (size_t)Gg*384);
  ushort* wT1lo = wT1hi + 3*D*D;
  ushort* wT2hi = wT1lo + 3*D*D;
  ushort* wT2lo = wT2hi + 3*D*D;
  ushort* weHi  = wT2lo + 3*D*D;      // [3][128][16]
  ushort* weLo  = weHi + 3*128*16;
  int*    flag  = (int*)(weLo + 3*128*16);
  int*    deg     = flag + 1;
  int*    rs      = deg + Nn;        // N+1
  int*    cursor  = rs + Nn + 1;
  int*    bsum    = cursor + Nn;
  int*    boff    = bsum + 256;
  int2*   spp     = (int2*)(boff + 256);

  detect_kernel<<<1,256,0,stream>>>((const uint*)x_in, flag);

  // CSR build (once; dst/src invariant across layers)
  int NB = (Nn + 511) / 512;
  hipMemsetAsync(deg, 0, (size_t)Nn*sizeof(int), stream);
  hist_kernel<<<(Ee+255)/256,256,0,stream>>>(dstp, deg, Ee);
  scan1_kernel<<<NB,256,0,stream>>>(deg, rs, bsum, Nn);
  scan2_kernel<<<1,256,0,stream>>>(bsum, boff, NB);
  scan3_kernel<<<(Nn+255)/256,256,0,stream>>>(rs, boff, cursor, Nn, Ee);
  scatter_kernel<<<(Ee+255)/256,256,0,stream>>>(dstp, srcp, cursor, spp, Ee);

  trans_kernel<<<192,256,0,stream>>>(w1p, wT1hi, wT1lo, flag);
  trans_kernel<<<192,256,0,stream>>>(w2p, wT2hi, wT2lo, flag);
  trans_edge_kernel<<<24,256,0,stream>>>(ew, weHi, weLo, flag);

  int mlpGrid  = (Nn + 63) / 64;    // 782
  int edgeGrid = 2048;              // grid-stride, ~3 node-pairs per wave
  float* xcur = nullptr;
  for (int i = 0; i < 3; i++){
    float* out = (i == 1) ? C : B;    // L0->B, L1->C, L2->B
    if (i == 0)
      edge_agg_kernel<true ><<<edgeGrid,256,0,stream>>>(spp, rs, eattr,
                                                        weHi + (size_t)i*2048, weLo + (size_t)i*2048,
                                                        eb, vn, epsp, i, x_in, nullptr, A, Nn, flag);
    else
      edge_agg_kernel<false><<<edgeGrid,256,0,stream>>>(spp, rs, eattr,
                                                        weHi + (size_t)i*2048, weLo + (size_t)i*2048,
                                                        eb, vn, epsp, i, nullptr, xcur, A, Nn, flag);
    mlp_fused<<<mlpGrid,256,0,stream>>>(A,
                                        wT1hi + (size_t)i*D*D, wT1lo + (size_t)i*D*D,
                                        wT2hi + (size_t)i*D*D, wT2lo + (size_t)i*D*D,
                                        b1p, b2p, i, out, Nn, flag);
    pool_kernel<<<Gg,512,0,stream>>>(out, batch, Nn, gbuf, i*D);
    xcur = out;
  }
  head_kernel<<<Gg,256,0,stream>>>(gbuf, lw1, lb1, ln1g, ln1b,
                                   lw2, lb2, ln2g, ln2b, owp, obp, d_out, flag);
}

// Round 9
// 736.972 us; speedup vs baseline: 1.2137x; 1.0834x over previous
//
#include <hip/hip_runtime.h>

typedef unsigned int uint;
typedef unsigned short ushort;
typedef __attribute__((ext_vector_type(8))) short short8;
typedef __attribute__((ext_vector_type(4))) float f32x4;
typedef __attribute__((ext_vector_type(2))) float f32x2;

#define D 128

__device__ __forceinline__ float bf2f(ushort h){ return __uint_as_float(((uint)h)<<16); }
__device__ __forceinline__ ushort f2bf(float f){
  uint u = __float_as_uint(f);
  u += 0x7fff + ((u >> 16) & 1);   // RNE
  return (ushort)(u >> 16);
}
__device__ __forceinline__ float ldf(const void* p, long i, int bf){
  return bf ? bf2f(((const ushort*)p)[i]) : ((const float*)p)[i];
}
__device__ __forceinline__ int imin(int a, int b){ return a < b ? a : b; }

// ---------------- dtype detection ----------------
__global__ __launch_bounds__(256) void detect_kernel(const uint* __restrict__ xw,
                                                     int* __restrict__ flag){
  __shared__ int cnt;
  if (threadIdx.x == 0) cnt = 0;
  __syncthreads();
  uint w = xw[threadIdx.x];
  int ef = (int)((w >> 7) & 0xffu);
  if (ef >= 90 && ef <= 142) atomicAdd(&cnt, 1);
  __syncthreads();
  if (threadIdx.x == 0) flag[0] = (cnt >= 128) ? 1 : 0;
}

// ---------------- CSR build (dst/src are layer-invariant) ----------------
__global__ __launch_bounds__(256) void hist_kernel(const int* __restrict__ dst,
                                                   int* __restrict__ deg, int E_){
  int e = blockIdx.x*256 + threadIdx.x;
  if (e < E_) atomicAdd(&deg[dst[e]], 1);
}

__global__ __launch_bounds__(256) void scan1_kernel(const int* __restrict__ deg,
                                                    int* __restrict__ rs,
                                                    int* __restrict__ bsum, int Nn){
  __shared__ int s[256];
  int tid = threadIdx.x;
  int base = blockIdx.x*512;
  int i0 = base + 2*tid, i1 = i0 + 1;
  int a = (i0 < Nn) ? deg[i0] : 0;
  int b = (i1 < Nn) ? deg[i1] : 0;
  int p = a + b;
  s[tid] = p; __syncthreads();
  for (int off = 1; off < 256; off <<= 1){
    int t = (tid >= off) ? s[tid-off] : 0;
    __syncthreads();
    s[tid] += t;
    __syncthreads();
  }
  int ex = s[tid] - p;
  if (i0 < Nn) rs[i0] = ex;
  if (i1 < Nn) rs[i1] = ex + a;
  if (tid == 255) bsum[blockIdx.x] = s[255];
}

__global__ __launch_bounds__(256) void scan2_kernel(const int* __restrict__ bsum,
                                                    int* __restrict__ boff, int NB){
  __shared__ int s[256];
  int tid = threadIdx.x;
  int v = (tid < NB) ? bsum[tid] : 0;
  s[tid] = v; __syncthreads();
  for (int off = 1; off < 256; off <<= 1){
    int t = (tid >= off) ? s[tid-off] : 0;
    __syncthreads();
    s[tid] += t;
    __syncthreads();
  }
  boff[tid] = s[tid] - v;
}

__global__ __launch_bounds__(256) void scan3_kernel(int* __restrict__ rs,
                                                    const int* __restrict__ boff,
                                                    int* __restrict__ cursor,
                                                    int Nn, int E_){
  int i = blockIdx.x*256 + threadIdx.x;
  if (i < Nn){
    int v = rs[i] + boff[i >> 9];
    rs[i] = v;
    cursor[i] = v;
  }
  if (i == 0) rs[Nn] = E_;
}

__global__ __launch_bounds__(256) void scatter_kernel(const int* __restrict__ dst,
                                                      const int* __restrict__ src,
                                                      int* __restrict__ cursor,
                                                      int2* __restrict__ spp, int E_){
  int e = blockIdx.x*256 + threadIdx.x;
  if (e < E_){
    int pos = atomicAdd(&cursor[dst[e]], 1);
    spp[pos] = make_int2(src[e], e);
  }
}

// CSR-order repack: sarr[ii]=src, paHi/paLo[ii][16] = hi/lo bf16 of attr[perm[ii]]
__global__ __launch_bounds__(256) void pack_kernel(const int2* __restrict__ spp,
                                                   const void* __restrict__ eattr,
                                                   ushort* __restrict__ paHi,
                                                   ushort* __restrict__ paLo,
                                                   int* __restrict__ sarr,
                                                   int E_, const int* __restrict__ flag){
  int bf = flag[0];
  int ii = blockIdx.x*256 + threadIdx.x;
  if (ii >= E_) return;
  int2 p = spp[ii];
  sarr[ii] = p.x;
  ushort hv[16], lv[16];
  #pragma unroll
  for (int k = 0; k < 16; k++){
    float v = ldf(eattr, (long)p.y*16 + k, bf);
    ushort h = f2bf(v);
    hv[k] = h;
    lv[k] = f2bf(v - bf2f(h));
  }
  *(uint4*)(paHi + (long)ii*16)     = *(uint4*)&hv[0];
  *(uint4*)(paHi + (long)ii*16 + 8) = *(uint4*)&hv[8];
  *(uint4*)(paLo + (long)ii*16)     = *(uint4*)&lv[0];
  *(uint4*)(paLo + (long)ii*16 + 8) = *(uint4*)&lv[8];
}

// ---------------- MLP W transpose + hi/lo bf16 split ----------------
__global__ __launch_bounds__(256) void trans_kernel(const void* __restrict__ W,
                                                    ushort* __restrict__ hi,
                                                    ushort* __restrict__ lo,
                                                    const int* __restrict__ flag){
  int bf = flag[0];
  int idx = blockIdx.x*256 + threadIdx.x;   // grid covers 3*16384 exactly
  int l = idx >> 14, rem = idx & 16383, k = rem >> 7, n = rem & 127;
  float w = ldf(W, idx, bf);
  ushort h = f2bf(w);
  int di = (l << 14) | (n << 7) | k;
  hi[di] = h;
  lo[di] = f2bf(w - bf2f(h));
}

// edge-W transpose: in ew[l][k(16)][n(128)] -> out [l][n][k(16)] hi/lo bf16
__global__ __launch_bounds__(256) void trans_edge_kernel(const void* __restrict__ W,
                                                         ushort* __restrict__ hi,
                                                         ushort* __restrict__ lo,
                                                         const int* __restrict__ flag){
  int bf = flag[0];
  int idx = blockIdx.x*256 + threadIdx.x;   // grid covers 3*2048 exactly
  int l = idx >> 11, rem = idx & 2047, k = rem >> 7, n = rem & 127;
  float w = ldf(W, idx, bf);
  ushort h = f2bf(w);
  int di = (l << 11) | (n << 4) | k;
  hi[di] = h;
  lo[di] = f2bf(w - bf2f(h));
}

// ---------------- edge gather-aggregate + PRE combine (streaming attr/src) ----------------
// hpre[n] = (1+eps)*(x[n]+vn) + sum_{e:dst=n} relu(x[src]+vn + attr@W + b)
template<bool FIRST>
__global__ __launch_bounds__(256) void edge_agg_kernel(
    const int* __restrict__ sarr, const int* __restrict__ rs,
    const ushort* __restrict__ paHi, const ushort* __restrict__ paLo,  // [E][16] CSR order
    const ushort* __restrict__ weHi, const ushort* __restrict__ weLo,  // [128][16] this layer
    const void* __restrict__ eb, const void* __restrict__ vn,
    const void* __restrict__ epsp, int layer,
    const void* __restrict__ xin, const float* __restrict__ xws,
    float* __restrict__ hpre, int Nn, const int* __restrict__ flag)
{
  int bf = flag[0];
  __shared__ float eemb[4][16][132];      // per-wave scratch
  int lane = threadIdx.x & 63, wvi = threadIdx.x >> 6;
  int m_ = lane & 15, q = lane >> 4;      // MFMA coords
  int d0 = lane << 1;
  // loop-invariant B-frags
  short8 bW1[8], bW2[8];
  #pragma unroll
  for (int ci = 0; ci < 8; ci++){
    int c = ci*16 + m_;
    bW1[ci] = *(const short8*)(weHi + c*16 + (q&1)*8);
    bW2[ci] = *(const short8*)(weLo + c*16 + (q&1)*8);
  }
  const ushort* pa = (q < 2) ? paHi : paLo;   // hi rows of K for q<2, lo rows for q>=2
  f32x2 vn2, cv;
  vn2[0] = ldf(vn, (long)layer*128 + d0,     bf);
  vn2[1] = ldf(vn, (long)layer*128 + d0 + 1, bf);
  cv[0] = ldf(eb, (long)layer*128 + d0,     bf) + vn2[0];
  cv[1] = ldf(eb, (long)layer*128 + d0 + 1, bf) + vn2[1];
  float epsv = 1.f + ldf(epsp, layer, bf);
  const float* xp32 = FIRST ? (const float*)xin : xws;

  for (int n0 = (blockIdx.x*4 + wvi)*2; n0 < Nn; n0 += gridDim.x*8){
    int beg   = rs[n0];
    int split = rs[n0+1];
    int end   = (n0+2 <= Nn) ? rs[n0+2] : split;
    f32x2 accA = {0.f, 0.f}, accB = {0.f, 0.f};
    int scur = (beg < end) ? sarr[imin(beg + m_, end - 1)] : 0;

    for (int ii = beg; ii < end; ii += 16){
      // ---- A-frag: streaming CSR-order attr (no shfl, no cvt)
      short8 afrag = *(const short8*)(pa + (long)imin(ii + m_, end - 1)*16 + (q&1)*8);
      // ---- prefetch next chunk's src
      bool more = (ii + 16) < end;
      int snext = more ? sarr[imin(ii + 16 + m_, end - 1)] : scur;
      // ---- e_emb via MFMA, C -> wave LDS (skip W_lo when storage is bf16)
      #pragma unroll
      for (int ci = 0; ci < 8; ci++){
        f32x4 acc = {0.f,0.f,0.f,0.f};
        acc = __builtin_amdgcn_mfma_f32_16x16x32_bf16(afrag, bW1[ci], acc, 0, 0, 0);
        if (!bf) acc = __builtin_amdgcn_mfma_f32_16x16x32_bf16(afrag, bW2[ci], acc, 0, 0, 0);
        int c = ci*16 + m_;
        #pragma unroll
        for (int rg = 0; rg < 4; rg++) eemb[wvi][q*4+rg][c] = acc[rg];
      }
      // ---- combine in 8-edge batches: issue gathers first, then reduce
      #pragma unroll
      for (int jb = 0; jb < 2; jb++){
        int ss[8];
        #pragma unroll
        for (int j = 0; j < 8; j++) ss[j] = __shfl(scur, jb*8 + j);
        f32x2 xv[8];
        #pragma unroll
        for (int j = 0; j < 8; j++){
          if (FIRST && bf){
            uint u = *(const uint*)((const ushort*)xin + (long)ss[j]*D + d0);
            xv[j][0] = __uint_as_float(u << 16);
            xv[j][1] = __uint_as_float(u & 0xffff0000u);
          } else {
            xv[j] = *(const f32x2*)(xp32 + (long)ss[j]*D + d0);
          }
        }
        #pragma unroll
        for (int j = 0; j < 8; j++){
          int gidx = ii + jb*8 + j;
          f32x2 ee = *(const f32x2*)&eemb[wvi][jb*8 + j][d0];
          float r0 = fmaxf(cv[0] + xv[j][0] + ee[0], 0.f);
          float r1 = fmaxf(cv[1] + xv[j][1] + ee[1], 0.f);
          bool inA = gidx < split;
          bool inB = (!inA) && (gidx < end);
          accA[0] += inA ? r0 : 0.f;  accA[1] += inA ? r1 : 0.f;
          accB[0] += inB ? r0 : 0.f;  accB[1] += inB ? r1 : 0.f;
        }
      }
      scur = snext;
    }
    // ---- PRE combine + store both rows
    f32x2 xn;
    if (FIRST && bf){
      uint u = *(const uint*)((const ushort*)xin + (long)n0*D + d0);
      xn[0] = __uint_as_float(u << 16);
      xn[1] = __uint_as_float(u & 0xffff0000u);
    } else {
      xn = *(const f32x2*)(xp32 + (long)n0*D + d0);
    }
    f32x2 hp;
    hp[0] = epsv*(xn[0] + vn2[0]) + accA[0];
    hp[1] = epsv*(xn[1] + vn2[1]) + accA[1];
    *(f32x2*)(hpre + (long)n0*D + d0) = hp;
    if (n0 + 1 < Nn){
      f32x2 xm;
      if (FIRST && bf){
        uint u = *(const uint*)((const ushort*)xin + (long)(n0+1)*D + d0);
        xm[0] = __uint_as_float(u << 16);
        xm[1] = __uint_as_float(u & 0xffff0000u);
      } else {
        xm = *(const f32x2*)(xp32 + (long)(n0+1)*D + d0);
      }
      f32x2 hq;
      hq[0] = epsv*(xm[0] + vn2[0]) + accB[0];
      hq[1] = epsv*(xm[1] + vn2[1]) + accB[1];
      *(f32x2*)(hpre + (long)(n0+1)*D + d0) = hq;
    }
  }
}

// ---------------- fused node MLP + pooling epilogue ----------------
// out = relu(h@W1+b1)@W2+b2; gbuf[batch[r], colOff+c] += out[r][c]
__global__ __launch_bounds__(256) void mlp_fused(
    const float* __restrict__ hpre,
    const ushort* __restrict__ w1hi, const ushort* __restrict__ w1lo,
    const ushort* __restrict__ w2hi, const ushort* __restrict__ w2lo,
    const void* __restrict__ b1v, const void* __restrict__ b2v, int layer,
    float* __restrict__ outp, int Nn, const int* __restrict__ flag,
    const int* __restrict__ batch, float* __restrict__ gbuf, int colOff)
{
  int bf = flag[0];
  __shared__ ushort sbuf[2][64][136];   // hi plane / lo plane; reused for packed h1
  __shared__ float bias1[D], bias2[D];
  __shared__ int bseg[64];
  __shared__ float gpart[8][132];
  int tid = threadIdx.x;
  if (tid < D){
    bias1[tid] = ldf(b1v, (long)layer*D + tid, bf);
    bias2[tid] = ldf(b2v, (long)layer*D + tid, bf);
  }
  if (tid < 64){
    long rr = (long)blockIdx.x*64 + tid;
    bseg[tid] = batch[(rr < Nn) ? rr : (Nn - 1)];
  }
  for (int i = tid; i < 8*132; i += 256) ((float*)gpart)[i] = 0.f;
  int srow = tid >> 2, scb = (tid & 3) << 5;
  long r = (long)blockIdx.x*64 + srow;
  {
    float hv[32];
    if (r < Nn){
      const float* xp = hpre + r*D + scb;
      #pragma unroll
      for (int j = 0; j < 32; j++) hv[j] = xp[j];
    } else {
      #pragma unroll
      for (int j = 0; j < 32; j++) hv[j] = 0.f;
    }
    uint* rowHi = (uint*)&sbuf[0][srow][0];
    uint* rowLo = (uint*)&sbuf[1][srow][0];
    #pragma unroll
    for (int j2 = 0; j2 < 16; j2++){
      float v0 = hv[2*j2], v1 = hv[2*j2+1];
      ushort h0 = f2bf(v0), h1 = f2bf(v1);
      ushort l0 = f2bf(v0 - bf2f(h0)), l1 = f2bf(v1 - bf2f(h1));
      rowHi[(scb>>1) + j2] = (uint)h0 | ((uint)h1 << 16);
      rowLo[(scb>>1) + j2] = (uint)l0 | ((uint)l1 << 16);
    }
  }
  __syncthreads();

  int bmin = bseg[0], bmax = bseg[63];
  int nseg = bmax - bmin + 1;
  bool useL = (nseg <= 8);

  int lane = tid & 63, wvi = tid >> 6;
  int m = lane & 15, kq = lane >> 4;
  int lr = wvi*16 + m;
  short8 aHi[4], aLo[4];
  #pragma unroll
  for (int ki = 0; ki < 4; ki++){
    aHi[ki] = *(const short8*)&sbuf[0][lr][ki*32 + kq*8];
    aLo[ki] = *(const short8*)&sbuf[1][lr][ki*32 + kq*8];
  }
  float h1[8][4];
  #pragma unroll
  for (int ci = 0; ci < 8; ci++){
    int c = ci*16 + m;
    f32x4 acc;
    float bv = bias1[c];
    acc[0] = bv; acc[1] = bv; acc[2] = bv; acc[3] = bv;
    const ushort* bp = w1hi + ((long)c << 7) + kq*8;
    #pragma unroll
    for (int ki = 0; ki < 4; ki++){
      short8 bfr = *(const short8*)(bp + ki*32);
      acc = __builtin_amdgcn_mfma_f32_16x16x32_bf16(aHi[ki], bfr, acc, 0, 0, 0);
      acc = __builtin_amdgcn_mfma_f32_16x16x32_bf16(aLo[ki], bfr, acc, 0, 0, 0);
    }
    if (!bf){
      const ushort* blp = w1lo + ((long)c << 7) + kq*8;
      #pragma unroll
      for (int ki = 0; ki < 4; ki++){
        short8 blr = *(const short8*)(blp + ki*32);
        acc = __builtin_amdgcn_mfma_f32_16x16x32_bf16(aHi[ki], blr, acc, 0, 0, 0);
      }
    }
    #pragma unroll
    for (int rg = 0; rg < 4; rg++) h1[ci][rg] = fmaxf(acc[rg], 0.f);
  }
  __syncthreads();
  uint* h1p = (uint*)&sbuf[0][0][0];
  #pragma unroll
  for (int ci = 0; ci < 8; ci++){
    int c = ci*16 + m;
    #pragma unroll
    for (int rg = 0; rg < 4; rg++){
      int rl = wvi*16 + kq*4 + rg;
      float v = h1[ci][rg];
      ushort hi_ = f2bf(v);
      ushort lo_ = f2bf(v - bf2f(hi_));
      h1p[rl*132 + c] = ((uint)hi_ << 16) | (uint)lo_;
    }
  }
  __syncthreads();
  #pragma unroll
  for (int ki = 0; ki < 4; ki++){
    const uint* up = h1p + lr*132 + ki*32 + kq*8;
    uint4 ua = *(const uint4*)up;
    uint4 ub = *(const uint4*)(up + 4);
    uint uu[8] = {ua.x,ua.y,ua.z,ua.w, ub.x,ub.y,ub.z,ub.w};
    short8 ah, al;
    #pragma unroll
    for (int t = 0; t < 8; t++){
      ah[t] = (short)(uu[t] >> 16);
      al[t] = (short)(uu[t] & 0xffffu);
    }
    aHi[ki] = ah; aLo[ki] = al;
  }
  int rl0 = wvi*16 + kq*4;
  long rowBase = (long)blockIdx.x*64 + rl0;
  int s0 = bseg[rl0], s3 = bseg[rl0+3];
  #pragma unroll
  for (int ci = 0; ci < 8; ci++){
    int c = ci*16 + m;
    f32x4 acc;
    float bv = bias2[c];
    acc[0] = bv; acc[1] = bv; acc[2] = bv; acc[3] = bv;
    const ushort* bp = w2hi + ((long)c << 7) + kq*8;
    #pragma unroll
    for (int ki = 0; ki < 4; ki++){
      short8 bfr = *(const short8*)(bp + ki*32);
      acc = __builtin_amdgcn_mfma_f32_16x16x32_bf16(aHi[ki], bfr, acc, 0, 0, 0);
      acc = __builtin_amdgcn_mfma_f32_16x16x32_bf16(aLo[ki], bfr, acc, 0, 0, 0);
    }
    if (!bf){
      const ushort* blp = w2lo + ((long)c << 7) + kq*8;
      #pragma unroll
      for (int ki = 0; ki < 4; ki++){
        short8 blr = *(const short8*)(blp + ki*32);
        acc = __builtin_amdgcn_mfma_f32_16x16x32_bf16(aHi[ki], blr, acc, 0, 0, 0);
      }
    }
    #pragma unroll
    for (int rg = 0; rg < 4; rg++){
      long orow = rowBase + rg;
      if (orow < Nn) outp[orow*D + c] = acc[rg];
    }
    // ---- pooling contribution
    if (useL){
      if (s0 == s3 && rowBase + 3 < Nn){
        atomicAdd(&gpart[s0 - bmin][c], acc[0] + acc[1] + acc[2] + acc[3]);
      } else {
        #pragma unroll
        for (int rg = 0; rg < 4; rg++){
          if (rowBase + rg < Nn)
            atomicAdd(&gpart[bseg[rl0+rg] - bmin][c], acc[rg]);
        }
      }
    } else {
      #pragma unroll
      for (int rg = 0; rg < 4; rg++){
        if (rowBase + rg < Nn)
          unsafeAtomicAdd(&gbuf[(long)bseg[rl0+rg]*384 + colOff + c], acc[rg]);
      }
    }
  }
  if (useL){
    __syncthreads();
    if (tid < 128){
      for (int s = 0; s < nseg; s++){
        float v = gpart[s][tid];
        if (v != 0.f)
          unsafeAtomicAdd(&gbuf[(long)(bmin + s)*384 + colOff + tid], v);
      }
    }
  }
}

// ---------------- head: Linear->LN->ReLU x2 -> Linear ----------------
__global__ __launch_bounds__(256) void head_kernel(
    const float* __restrict__ g,
    const void* __restrict__ w1, const void* __restrict__ b1,
    const void* __restrict__ g1, const void* __restrict__ be1,
    const void* __restrict__ w2, const void* __restrict__ b2,
    const void* __restrict__ g2, const void* __restrict__ be2,
    const void* __restrict__ ow, const void* __restrict__ ob,
    void* __restrict__ outp, const int* __restrict__ flag)
{
  int bf = flag[0];
  __shared__ float grow[384];
  __shared__ float h1[256];
  __shared__ float h2[128];
  __shared__ float redA[4], redB[4], stats[2];
  int b = blockIdx.x, tid = threadIdx.x;
  for (int i = tid; i < 384; i += 256) grow[i] = g[(long)b*384 + i];
  __syncthreads();
  float v = ldf(b1, tid, bf);
  for (int k = 0; k < 384; k++) v += grow[k] * ldf(w1, (long)k*256 + tid, bf);
  float s = v, s2 = v*v;
  for (int o = 32; o; o >>= 1){ s += __shfl_down(s,o); s2 += __shfl_down(s2,o); }
  if ((tid & 63) == 0){ redA[tid>>6] = s; redB[tid>>6] = s2; }
  __syncthreads();
  if (tid == 0){
    float S = redA[0]+redA[1]+redA[2]+redA[3];
    float S2 = redB[0]+redB[1]+redB[2]+redB[3];
    float mu = S / 256.f;
    stats[0] = mu; stats[1] = rsqrtf(S2/256.f - mu*mu + 1e-5f);
  }
  __syncthreads();
  float y = (v - stats[0]) * stats[1] * ldf(g1, tid, bf) + ldf(be1, tid, bf);
  h1[tid] = fmaxf(y, 0.f);
  __syncthreads();
  float v2 = 0.f;
  if (tid < 128){
    v2 = ldf(b2, tid, bf);
    for (int k = 0; k < 256; k++) v2 += h1[k] * ldf(w2, (long)k*128 + tid, bf);
  }
  float t = (tid < 128) ? v2 : 0.f;
  s = t; s2 = t*t;
  for (int o = 32; o; o >>= 1){ s += __shfl_down(s,o); s2 += __shfl_down(s2,o); }
  if ((tid & 63) == 0){ redA[tid>>6] = s; redB[tid>>6] = s2; }
  __syncthreads();
  if (tid == 0){
    float S = redA[0]+redA[1]+redA[2]+redA[3];
    float S2 = redB[0]+redB[1]+redB[2]+redB[3];
    float mu = S / 128.f;
    stats[0] = mu; stats[1] = rsqrtf(S2/128.f - mu*mu + 1e-5f);
  }
  __syncthreads();
  if (tid < 128){
    float y2 = (v2 - stats[0]) * stats[1] * ldf(g2, tid, bf) + ldf(be2, tid, bf);
    h2[tid] = fmaxf(y2, 0.f);
  }
  __syncthreads();
  float p = (tid < 128) ? h2[tid] * ldf(ow, tid, bf) : 0.f;
  s = p;
  for (int o = 32; o; o >>= 1) s += __shfl_down(s, o);
  if ((tid & 63) == 0) redA[tid>>6] = s;
  __syncthreads();
  if (tid == 0){
    float r = redA[0]+redA[1]+redA[2]+redA[3] + ldf(ob, 0, bf);
    if (bf) ((ushort*)outp)[b] = f2bf(r);
    else    ((float*)outp)[b]  = r;
  }
}

extern "C" void kernel_launch(void* const* d_in, const int* in_sizes, int n_in,
                              void* d_out, int out_size, void* d_ws, size_t ws_size,
                              hipStream_t stream)
{
  const void* x_in  = d_in[0];
  const int*  eidx  = (const int*)d_in[1];
  const void* eattr = d_in[2];
  const int*  batch = (const int*)d_in[3];
  const void* vn    = d_in[4];
  const void* ew    = d_in[5];
  const void* eb    = d_in[6];
  const void* epsp  = d_in[7];
  const void* w1p   = d_in[8];
  const void* b1p   = d_in[9];
  const void* w2p   = d_in[10];
  const void* b2p   = d_in[11];
  const void* lw1   = d_in[12];
  const void* lb1   = d_in[13];
  const void* ln1g  = d_in[14];
  const void* ln1b  = d_in[15];
  const void* lw2   = d_in[16];
  const void* lb2   = d_in[17];
  const void* ln2g  = d_in[18];
  const void* ln2b  = d_in[19];
  const void* owp   = d_in[20];
  const void* obp   = d_in[21];

  int Nn = in_sizes[0] / D;     // 50000
  int Ee = in_sizes[1] / 2;     // 600000
  int Gg = out_size;            // 512
  const int* srcp = eidx;
  const int* dstp = eidx + Ee;

  float*  A     = (float*)d_ws;                 // hpre scratch
  float*  B     = A + (size_t)Nn*D;             // layer in/out ping-pong (single buffer)
  float*  gbuf  = B + (size_t)Nn*D;
  ushort* wT1hi = (ushort*)(gbuf + (size_t)Gg*384);
  ushort* wT1lo = wT1hi + 3*D*D;
  ushort* wT2hi = wT1lo + 3*D*D;
  ushort* wT2lo = wT2hi + 3*D*D;
  ushort* weHi  = wT2lo + 3*D*D;      // [3][128][16]
  ushort* weLo  = weHi + 3*128*16;
  int*    flag  = (int*)(weLo + 3*128*16);
  int*    deg     = flag + 1;
  int*    rs      = deg + Nn;        // N+1
  int*    cursor  = rs + Nn + 1;
  int*    bsum    = cursor + Nn;
  int*    boff    = bsum + 256;
  int2*   spp     = (int2*)(boff + 256);          // [E]
  int*    sarr    = (int*)(spp + Ee);             // [E]
  ushort* paHi    = (ushort*)(sarr + Ee);         // [E][16]
  ushort* paLo    = paHi + (size_t)Ee*16;         // [E][16]

  detect_kernel<<<1,256,0,stream>>>((const uint*)x_in, flag);

  // CSR build (once; dst/src invariant across layers)
  int NB = (Nn + 511) / 512;
  hipMemsetAsync(deg, 0, (size_t)Nn*sizeof(int), stream);
  hipMemsetAsync(gbuf, 0, (size_t)Gg*384*sizeof(float), stream);
  hist_kernel<<<(Ee+255)/256,256,0,stream>>>(dstp, deg, Ee);
  scan1_kernel<<<NB,256,0,stream>>>(deg, rs, bsum, Nn);
  scan2_kernel<<<1,256,0,stream>>>(bsum, boff, NB);
  scan3_kernel<<<(Nn+255)/256,256,0,stream>>>(rs, boff, cursor, Nn, Ee);
  scatter_kernel<<<(Ee+255)/256,256,0,stream>>>(dstp, srcp, cursor, spp, Ee);
  pack_kernel<<<(Ee+255)/256,256,0,stream>>>(spp, eattr, paHi, paLo, sarr, Ee, flag);

  trans_kernel<<<192,256,0,stream>>>(w1p, wT1hi, wT1lo, flag);
  trans_kernel<<<192,256,0,stream>>>(w2p, wT2hi, wT2lo, flag);
  trans_edge_kernel<<<24,256,0,stream>>>(ew, weHi, weLo, flag);

  int mlpGrid  = (Nn + 63) / 64;    // 782
  int edgeGrid = 2048;              // grid-stride, ~3 node-pairs per wave
  for (int i = 0; i < 3; i++){
    if (i == 0)
      edge_agg_kernel<true ><<<edgeGrid,256,0,stream>>>(sarr, rs, paHi, paLo,
                                                        weHi + (size_t)i*2048, weLo + (size_t)i*2048,
                                                        eb, vn, epsp, i, x_in, nullptr, A, Nn, flag);
    else
      edge_agg_kernel<false><<<edgeGrid,256,0,stream>>>(sarr, rs, paHi, paLo,
                                                        weHi + (size_t)i*2048, weLo + (size_t)i*2048,
                                                        eb, vn, epsp, i, nullptr, B, A, Nn, flag);
    // MLP (+ fused pooling): reads A, writes B (old B content is dead)
    mlp_fused<<<mlpGrid,256,0,stream>>>(A,
                                        wT1hi + (size_t)i*D*D, wT1lo + (size_t)i*D*D,
                                        wT2hi + (size_t)i*D*D, wT2lo + (size_t)i*D*D,
                                        b1p, b2p, i, B, Nn, flag, batch, gbuf, i*D);
  }
  head_kernel<<<Gg,256,0,stream>>>(gbuf, lw1, lb1, ln1g, ln1b,
                                   lw2, lb2, ln2g, ln2b, owp, obp, d_out, flag);
}